// Round 7
// baseline (466.502 us; speedup 1.0000x reference)
//
#include <hip/hip_runtime.h>

// PointNet 2-stage fused pipeline, MI355X gfx950.  Round 7.
// k_stage2 v3: persistent blocks (1024 x 8 tiles), W3/W4 fragments held in
// VGPRs (128 regs/wave) -> zero per-tile B staging; full-K A tile (32KB)
// double-buffered via global_load_lds; 4 barriers/tile (was 16).
// pf4 [64][264] padded LDS (validated round 6); pf5 overlays pf4.
// launch_bounds(512,2): VGPR cap 256 (round-3 lesson: min-waves caps VGPRs).
// P1, mmv1, mmv2, sort: unchanged validated code.

#define NPTS 524288
#define NVOX 32768

typedef _Float16 f16;
typedef _Float16 f16x8 __attribute__((ext_vector_type(8)));
typedef float f32x4 __attribute__((ext_vector_type(4)));

#define GLDS16(g, l)                                                          \
  __builtin_amdgcn_global_load_lds(                                           \
      (const __attribute__((address_space(1))) unsigned int*)(const void*)(g),\
      (__attribute__((address_space(3))) unsigned int*)(void*)(l), 16, 0, 0)

// ---------- idx normalization: auto-detect int32 vs int64 storage ----------
__global__ void k_fixidx(const int* __restrict__ raw, int* __restrict__ out) {
  bool is64 = true;
#pragma unroll
  for (int k = 0; k < 32; ++k)
    if (raw[2 * k + 1] != 0) is64 = false;   // int64 high words all 0 (vals < 32768)
  int stride = gridDim.x * blockDim.x;
  for (int i = blockIdx.x * blockDim.x + threadIdx.x; i < NPTS; i += stride)
    out[i] = is64 ? raw[2 * i] : raw[i];
}

// ---------- counting sort ----------
__global__ void k_hist(const int* __restrict__ idx, int* __restrict__ counts) {
  int stride = gridDim.x * blockDim.x;
  for (int i = blockIdx.x * blockDim.x + threadIdx.x; i < NPTS; i += stride)
    atomicAdd(&counts[idx[i]], 1);
}

__global__ void k_scan(const int* __restrict__ counts, int* __restrict__ offsets) {
  __shared__ int part[1024];
  __shared__ int sums[32];
  int t = threadIdx.x;
  int loc[32];
  int s = 0;
#pragma unroll
  for (int j = 0; j < 32; ++j) { loc[j] = counts[t * 32 + j]; s += loc[j]; }
  part[t] = s;
  __syncthreads();
  if (t < 32) {
    int run = 0;
    for (int j = 0; j < 32; ++j) { int tmp = part[t * 32 + j]; part[t * 32 + j] = run; run += tmp; }
    sums[t] = run;
  }
  __syncthreads();
  if (t == 0) {
    int run = 0;
    for (int i = 0; i < 32; ++i) { int tmp = sums[i]; sums[i] = run; run += tmp; }
  }
  __syncthreads();
  int b = part[t] + sums[t >> 5];
#pragma unroll
  for (int j = 0; j < 32; ++j) { offsets[t * 32 + j] = b; b += loc[j]; }
  if (t == 1023) offsets[NVOX] = b;
}

__global__ void k_scat(const int* __restrict__ idx, const int* __restrict__ offsets,
                       int* __restrict__ cursor, int* __restrict__ sp, int* __restrict__ sv) {
  int stride = gridDim.x * blockDim.x;
  for (int i = blockIdx.x * blockDim.x + threadIdx.x; i < NPTS; i += stride) {
    int v = idx[i];
    int pos = offsets[v] + atomicAdd(&cursor[v], 1);
    sp[pos] = i;
    sv[pos] = v;
  }
}

// ---------- weight transpose+cast: Wt[n][k] = (f16)W[k][n] ----------
__global__ void k_wcast(const float* __restrict__ W, f16* __restrict__ Wt, int K, int N) {
  int g = blockIdx.x * blockDim.x + threadIdx.x;
  if (g >= K * N) return;
  int k = g / N, n = g % N;
  Wt[n * K + k] = (f16)W[g];
}

__global__ void k_castf(const float* __restrict__ in, f16* __restrict__ out, int n) {
  int stride = gridDim.x * blockDim.x;
  for (int i = blockIdx.x * blockDim.x + threadIdx.x; i < n; i += stride)
    out[i] = (f16)in[i];
}

// ---------- generic f16 MFMA GEMM (validated round-4 core) -----------------
// 256 thr, 4 waves 2x2, 128x128 tile; N=256 via NT column-half blocks.
// MODEA 0: A'[r]=A[tm*128+r]; MODEA 2: mlp1 on the fly (K=64).
// SCATTER: run-reduced sorted scatter-max; WRITEO: dense output.
template <int K, int N, int MODEA, bool SCATTER, bool OUTF32, bool WRITEO>
__global__ __launch_bounds__(256, 3) void k_gemm(
    const f16* __restrict__ A,
    const int* __restrict__ sv, const int* __restrict__ sp,
    const int* __restrict__ offs,
    const float* __restrict__ x, const float* __restrict__ W1, const float* __restrict__ b1,
    const f16* __restrict__ Bt,   // [N][K] pre-transposed
    const float* __restrict__ bias,
    f16* __restrict__ Of16, float* __restrict__ Of32, int row0) {
  constexpr int NT = N / 128;
  __shared__ __align__(16) char smem[32768];
  __shared__ float xs[MODEA == 2 ? 768 : 1];
  __shared__ int svp[MODEA == 2 ? 128 : 1];
  __shared__ int svx[SCATTER ? 128 : 1];
  f16* As = (f16*)smem;            // [128][64] per K-tile, 16B chunks XOR-swizzled
  f16* Bs = As + 128 * 64;

  int nwg = gridDim.x;             // all grids are multiples of 8
  int bid = blockIdx.x;
  int q = nwg >> 3;
  int swz = (bid & 7) * q + (bid >> 3);   // bijective XCD swizzle
  int tm = swz / NT, tn = swz % NT;
  int t = threadIdx.x;

  if (MODEA == 2) { if (t < 128) svp[t] = sp[row0 + tm * 128 + t]; }
  if (SCATTER) { if (t < 128) svx[t] = sv[row0 + tm * 128 + t]; }
  if (MODEA == 2) __syncthreads();

  int l = t & 63, w = t >> 6;
  int wm = w >> 1, wn = w & 1;
  int lrow = l & 15, lk = l >> 4;
  f32x4 acc[4][4] = {};

  constexpr int KT = K / 64;
#pragma unroll
  for (int kt = 0; kt < KT; ++kt) {
    int k0 = kt * 64;
#pragma unroll
    for (int i = 0; i < 4; ++i) {
      int n = i * 32 + (t >> 3);
      int clog = (t & 7) ^ (n & 7);
      GLDS16(Bt + (size_t)(tn * 128 + n) * K + k0 + clog * 8, Bs + i * 2048 + t * 8);
    }
    if constexpr (MODEA == 2) {
      for (int g = t; g < 768; g += 256) xs[g] = x[(size_t)svp[g / 6] * 6 + (g % 6)];
      __syncthreads();
      int j = t & 63;
      float wv[6];
#pragma unroll
      for (int i = 0; i < 6; ++i) wv[i] = W1[i * 64 + j];
      float bb = b1[j];
      int rb = (t >> 6) * 32;
#pragma unroll
      for (int rr = 0; rr < 32; ++rr) {
        int row = rb + rr;
        float a = bb;
#pragma unroll
        for (int i = 0; i < 6; ++i) a += xs[row * 6 + i] * wv[i];
        As[row * 64 + (((j >> 3) ^ (row & 7)) << 3) + (j & 7)] = (f16)fmaxf(a, 0.f);
      }
    } else {
#pragma unroll
      for (int i = 0; i < 4; ++i) {
        int row = i * 32 + (t >> 3);
        int clog = (t & 7) ^ (row & 7);
        GLDS16(A + (size_t)(tm * 128 + row) * K + k0 + clog * 8, As + i * 2048 + t * 8);
      }
    }
    __syncthreads();
#pragma unroll
    for (int ks = 0; ks < 2; ++ks) {
      f16x8 af[4], bf[4];
#pragma unroll
      for (int m = 0; m < 4; ++m) {
        int row = wm * 64 + m * 16 + lrow;
        int cp = (ks * 4 + lk) ^ (row & 7);
        af[m] = *(const f16x8*)(As + row * 64 + cp * 8);
      }
#pragma unroll
      for (int n = 0; n < 4; ++n) {
        int col = wn * 64 + n * 16 + lrow;
        int cp = (ks * 4 + lk) ^ (col & 7);
        bf[n] = *(const f16x8*)(Bs + col * 64 + cp * 8);
      }
#pragma unroll
      for (int m = 0; m < 4; ++m)
#pragma unroll
        for (int n = 0; n < 4; ++n)
          acc[m][n] = __builtin_amdgcn_mfma_f32_16x16x32_f16(af[m], bf[n], acc[m][n], 0, 0, 0);
    }
    __syncthreads();
  }

  if constexpr (WRITEO) {
#pragma unroll
    for (int m = 0; m < 4; ++m)
#pragma unroll
      for (int n = 0; n < 4; ++n)
#pragma unroll
        for (int j = 0; j < 4; ++j) {
          int row = wm * 64 + m * 16 + lk * 4 + j;       // C/D: row=(l>>4)*4+j
          int gc  = tn * 128 + wn * 64 + n * 16 + lrow;  // col=l&15
          float val = fmaxf(acc[m][n][j] + bias[gc], 0.f);
          if constexpr (OUTF32) Of32[(size_t)(tm * 128 + row) * N + gc] = val;
          else                  Of16[(size_t)(tm * 128 + row) * N + gc] = (f16)val;
        }
  }

  if constexpr (SCATTER) {
    f16* tile = (f16*)smem;   // [128][128] f16 (32KB, reuses As/Bs)
#pragma unroll
    for (int m = 0; m < 4; ++m)
#pragma unroll
      for (int n = 0; n < 4; ++n)
#pragma unroll
        for (int j = 0; j < 4; ++j) {
          int row = wm * 64 + m * 16 + lk * 4 + j;
          int col = wn * 64 + n * 16 + lrow;
          tile[row * 128 + col] =
              (f16)fmaxf(acc[m][n][j] + bias[tn * 128 + col], 0.f);
        }
    __syncthreads();
    int c = t & 127, h = t >> 7;    // 2 segments x 64 rows
    int r0l = h * 64;
    int gc = tn * 128 + c;
    int grow0 = row0 + tm * 128 + r0l;
    float run = 0.f;
    int curv = svx[r0l];
    for (int r = r0l; r < r0l + 64; ++r) {
      int v = svx[r];
      if (v != curv) {
        bool inter = (offs[curv] >= grow0) && (offs[curv + 1] <= grow0 + 64);
        if (inter) Of32[(size_t)curv * N + gc] = run;
        else atomicMax((int*)&Of32[(size_t)curv * N + gc], __float_as_int(run));
        curv = v; run = 0.f;
      }
      run = fmaxf(run, (float)tile[r * 128 + c]);
    }
    bool inter = (offs[curv] >= grow0) && (offs[curv + 1] <= grow0 + 64);
    if (inter) Of32[(size_t)curv * N + gc] = run;
    else atomicMax((int*)&Of32[(size_t)curv * N + gc], __float_as_int(run));
  }
}

// ---------- fused stage 2 v3: persistent, weights in registers -------------
// 512 thr / 8 waves; wave w owns output cols [w*32, w*32+32).
// Per block: load W3/W4 frags into VGPRs once, then loop tpb tiles of 64 rows:
//   stage full-K A (dbuf) -> mm3 (B=regs) -> pf4 LDS -> mm4 (A=pf4, B=regs)
//   -> pf5 (overlays pf4) -> run-reduced scatter-max.
__global__ __launch_bounds__(512, 2) void k_stage2(
    const f16* __restrict__ pf2, const f16* __restrict__ occ1,
    const int* __restrict__ sv, const int* __restrict__ offs,
    const f16* __restrict__ W3t, const float* __restrict__ b3,
    const f16* __restrict__ W4t, const float* __restrict__ b4,
    float* __restrict__ vox2f, int row0, int tpb) {
  __shared__ __align__(16) f16 AsBuf[2][64 * 256];   // 64KB, chunk-XOR swizzled
  __shared__ __align__(16) f16 pf4[64 * 264];        // 33KB padded; pf5 overlays
  __shared__ int svx[64];
  f16* pf5 = pf4;

  int nwg = gridDim.x;
  int bid = blockIdx.x;
  int q = nwg >> 3;
  int bm = (bid & 7) * q + (bid >> 3);   // bijective XCD swizzle (block index)
  int t = threadIdx.x;
  int l = t & 63, w = t >> 6;
  int lrow = l & 15, lk = l >> 4;

  // ---- persistent B fragments: col = w*32+n*16+lrow, kchunk = ks*4+lk -----
  f16x8 bf3[4][2][2], bf4[4][2][2];   // [kt][ks][n]
  float b3v[2], b4v[2];
#pragma unroll
  for (int n = 0; n < 2; ++n) {
    int col = w * 32 + n * 16 + lrow;
    b3v[n] = b3[col];
    b4v[n] = b4[col];
#pragma unroll
    for (int kt = 0; kt < 4; ++kt)
#pragma unroll
      for (int ks = 0; ks < 2; ++ks) {
        int koff = kt * 64 + (ks * 4 + lk) * 8;
        bf3[kt][ks][n] = *(const f16x8*)(W3t + (size_t)col * 256 + koff);
        bf4[kt][ks][n] = *(const f16x8*)(W4t + (size_t)col * 256 + koff);
      }
  }

  // stage full-K A for tile lt into dst: [64 rows][32 chunks], slot = c^(row&7)
  auto STAGE = [&](int lt, f16* dst) {
#pragma unroll
    for (int ii = 0; ii < 4; ++ii) {
      int g = ii * 512 + t;
      int row = g >> 5, cs = g & 31;
      int cl = cs ^ (row & 7);                 // source chunk (low-3-bit XOR)
      const f16* src;
      if (cl < 16) src = occ1 + (size_t)sv[row0 + lt * 64 + row] * 128 + cl * 8;
      else         src = pf2 + (size_t)(lt * 64 + row) * 128 + (cl - 16) * 8;
      GLDS16(src, dst + g * 8);
    }
  };

  int t0 = bm * tpb;
  int cur = 0;
  STAGE(t0, AsBuf[0]);
  __syncthreads();                             // drain: As[0] ready

  for (int i = 0; i < tpb; ++i) {
    int lt = t0 + i;
    const f16* Acur = AsBuf[cur];

    // ---------------- mm3: pf4 = relu(concat(occ1[sv],pf2) @ W3 + b3) ------
    {
      f32x4 acc[4][2] = {};
#pragma unroll
      for (int kt = 0; kt < 4; ++kt)
#pragma unroll
        for (int ks = 0; ks < 2; ++ks) {
          f16x8 af[4];
#pragma unroll
          for (int m = 0; m < 4; ++m) {
            int row = m * 16 + lrow;
            int slot = kt * 8 + (((ks * 4 + lk)) ^ (row & 7));
            af[m] = *(const f16x8*)(Acur + row * 256 + slot * 8);
          }
#pragma unroll
          for (int m = 0; m < 4; ++m)
#pragma unroll
            for (int n = 0; n < 2; ++n)
              acc[m][n] = __builtin_amdgcn_mfma_f32_16x16x32_f16(
                  af[m], bf3[kt][ks][n], acc[m][n], 0, 0, 0);
        }
#pragma unroll
      for (int m = 0; m < 4; ++m)
#pragma unroll
        for (int n = 0; n < 2; ++n)
#pragma unroll
          for (int j = 0; j < 4; ++j) {
            int row  = m * 16 + lk * 4 + j;    // C/D: row=(l>>4)*4+j, col=l&15
            int colg = w * 32 + n * 16 + lrow;
            pf4[row * 264 + colg] = (f16)fmaxf(acc[m][n][j] + b3v[n], 0.f);
          }
    }
    __syncthreads();                           // pf4 ready; As[cur] consumed

    if (i + 1 < tpb) STAGE(lt + 1, AsBuf[cur ^ 1]);   // hide under mm4

    // ---------------- mm4: pf5 = relu(pf4 @ W4 + b4) -----------------------
    {
      f32x4 acc[4][2] = {};
#pragma unroll
      for (int kt = 0; kt < 4; ++kt)
#pragma unroll
        for (int ks = 0; ks < 2; ++ks) {
          f16x8 af[4];
#pragma unroll
          for (int m = 0; m < 4; ++m) {
            int row = m * 16 + lrow;
            int chunk = kt * 8 + ks * 4 + lk;  // linear pf4 layout
            af[m] = *(const f16x8*)(pf4 + row * 264 + chunk * 8);
          }
#pragma unroll
          for (int m = 0; m < 4; ++m)
#pragma unroll
            for (int n = 0; n < 2; ++n)
              acc[m][n] = __builtin_amdgcn_mfma_f32_16x16x32_f16(
                  af[m], bf4[kt][ks][n], acc[m][n], 0, 0, 0);
        }
      __syncthreads();                         // all pf4 reads done
      if (t < 64) svx[t] = sv[row0 + lt * 64 + t];
#pragma unroll
      for (int m = 0; m < 4; ++m)
#pragma unroll
        for (int n = 0; n < 2; ++n)
#pragma unroll
          for (int j = 0; j < 4; ++j) {
            int row  = m * 16 + lk * 4 + j;
            int colg = w * 32 + n * 16 + lrow;
            pf5[row * 264 + colg] = (f16)fmaxf(acc[m][n][j] + b4v[n], 0.f);
          }
    }
    __syncthreads();                           // pf5 + svx ready

    // ---------------- scatter-max scan (validated round-6 logic) -----------
    {
      int c = t & 255, seg = t >> 8;           // 256 cols x 2 segs of 32 rows
      int r0l = seg * 32;
      int grow0 = row0 + lt * 64 + r0l;
      float run = 0.f;
      int curv = svx[r0l];
      for (int r = r0l; r < r0l + 32; ++r) {
        int v = svx[r];
        if (v != curv) {
          bool inter = (offs[curv] >= grow0) && (offs[curv + 1] <= grow0 + 32);
          if (inter) vox2f[(size_t)curv * 256 + c] = run;
          else atomicMax((int*)&vox2f[(size_t)curv * 256 + c], __float_as_int(run));
          curv = v; run = 0.f;
        }
        run = fmaxf(run, (float)pf5[r * 264 + c]);
      }
      bool inter = (offs[curv] >= grow0) && (offs[curv + 1] <= grow0 + 32);
      if (inter) vox2f[(size_t)curv * 256 + c] = run;
      else atomicMax((int*)&vox2f[(size_t)curv * 256 + c], __float_as_int(run));
    }
    __syncthreads();                           // scan done; As[next] drained
    cur ^= 1;
  }
}

extern "C" void kernel_launch(void* const* d_in, const int* in_sizes, int n_in,
                              void* d_out, int out_size, void* d_ws, size_t ws_size,
                              hipStream_t stream) {
  const float* x   = (const float*)d_in[0];
  const int*  idxr = (const int*)d_in[1];
  const float* W1  = (const float*)d_in[3];
  const float* b1  = (const float*)d_in[4];
  const float* W2  = (const float*)d_in[5];
  const float* b2  = (const float*)d_in[6];
  const float* Wv1 = (const float*)d_in[7];
  const float* bv1 = (const float*)d_in[8];
  const float* W3  = (const float*)d_in[9];
  const float* b3  = (const float*)d_in[10];
  const float* W4  = (const float*)d_in[11];
  const float* b4  = (const float*)d_in[12];
  const float* Wv2 = (const float*)d_in[13];
  const float* bv2 = (const float*)d_in[14];
  float* out = (float*)d_out;

  char* ws = (char*)d_ws;
  size_t off = 0;
  auto alloc = [&](size_t bytes) {
    void* p = ws + off;
    off = (off + bytes + 255) & ~(size_t)255;
    return p;
  };
  int* idx     = (int*)alloc((size_t)NPTS * 4);
  int* counts  = (int*)alloc((size_t)NVOX * 4);
  int* cursor  = (int*)alloc((size_t)NVOX * 4);
  int* offs    = (int*)alloc((size_t)(NVOX + 1) * 4);
  int* sp      = (int*)alloc((size_t)NPTS * 4);
  int* sv      = (int*)alloc((size_t)NPTS * 4);
  f16* W2t     = (f16*)alloc(64 * 128 * 2);
  f16* Wv1t    = (f16*)alloc(128 * 128 * 2);
  f16* W3t     = (f16*)alloc(256 * 256 * 2);
  f16* W4t     = (f16*)alloc(256 * 256 * 2);
  f16* Wv2t    = (f16*)alloc(256 * 256 * 2);
  float* vox1f = (float*)alloc((size_t)NVOX * 128 * 4);
  f16* vox1h   = (f16*)alloc((size_t)NVOX * 128 * 2);
  f16* occ1    = (f16*)alloc((size_t)NVOX * 128 * 2);
  float* vox2f = (float*)alloc((size_t)NVOX * 256 * 4);

  // adaptive: materialize pf2 fully if workspace allows, else chunked recompute
  size_t rem = (ws_size > off) ? ws_size - off : 0;
  bool PF2FULL = rem >= (size_t)NPTS * 256 + 4096;
  int CH = 65536;
  f16* pf2   = (f16*)alloc(PF2FULL ? (size_t)NPTS * 256 : (size_t)CH * 256);
  f16* vox2h = pf2;   // overlay: pf2/pf2c dead once stage2 done (16MB fits both)

  hipMemsetAsync(counts, 0, (size_t)NVOX * 4, stream);
  hipMemsetAsync(cursor, 0, (size_t)NVOX * 4, stream);
  hipMemsetAsync(vox1f, 0, (size_t)NVOX * 128 * 4, stream);
  hipMemsetAsync(vox2f, 0, (size_t)NVOX * 256 * 4, stream);

  k_fixidx<<<2048, 256, 0, stream>>>(idxr, idx);
  k_wcast<<<(64 * 128 + 255) / 256, 256, 0, stream>>>(W2, W2t, 64, 128);
  k_wcast<<<(128 * 128 + 255) / 256, 256, 0, stream>>>(Wv1, Wv1t, 128, 128);
  k_wcast<<<(256 * 256 + 255) / 256, 256, 0, stream>>>(W3, W3t, 256, 256);
  k_wcast<<<(256 * 256 + 255) / 256, 256, 0, stream>>>(W4, W4t, 256, 256);
  k_wcast<<<(256 * 256 + 255) / 256, 256, 0, stream>>>(Wv2, Wv2t, 256, 256);
  k_hist<<<2048, 256, 0, stream>>>(idx, counts);
  k_scan<<<1, 1024, 0, stream>>>(counts, offs);
  k_scat<<<2048, 256, 0, stream>>>(idx, offs, cursor, sp, sv);

  // P1: fused mlp1+mm2 + segment-max -> vox1f (also writes pf2 when it fits)
  if (PF2FULL)
    k_gemm<64, 128, 2, true, false, true><<<NPTS / 128, 256, 0, stream>>>(
        nullptr, sv, sp, offs, x, W1, b1, W2t, b2, pf2, vox1f, 0);
  else
    k_gemm<64, 128, 2, true, false, false><<<NPTS / 128, 256, 0, stream>>>(
        nullptr, sv, sp, offs, x, W1, b1, W2t, b2, nullptr, vox1f, 0);
  k_castf<<<2048, 256, 0, stream>>>(vox1f, vox1h, NVOX * 128);
  // mmv1: occ1 = relu(vox1 @ Wv1 + bv1)
  k_gemm<128, 128, 0, false, false, true><<<NVOX / 128, 256, 0, stream>>>(
      vox1h, nullptr, nullptr, nullptr, nullptr, nullptr, nullptr,
      Wv1t, bv1, occ1, nullptr, 0);

  // stage 2: persistent fused mm3+mm4+scatter (weights in VGPRs)
  if (PF2FULL) {
    k_stage2<<<1024, 512, 0, stream>>>(
        pf2, occ1, sv, offs, W3t, b3, W4t, b4, vox2f, 0, (NPTS / 64) / 1024);
  } else {
    for (int c = 0; c < NPTS / CH; ++c) {
      int row0 = c * CH;
      k_gemm<64, 128, 2, false, false, true><<<CH / 128, 256, 0, stream>>>(
          nullptr, nullptr, sp, nullptr, x, W1, b1, W2t, b2, pf2, nullptr, row0);
      k_stage2<<<1024, 512, 0, stream>>>(
          pf2, occ1, sv, offs, W3t, b3, W4t, b4, vox2f, row0, (CH / 64) / 1024);
    }
  }

  k_castf<<<2048, 256, 0, stream>>>(vox2f, vox2h, NVOX * 256);
  // mmv2: out = relu(vox2 @ Wv2 + bv2), f32 output via MFMA
  k_gemm<256, 256, 0, false, true, true><<<(NVOX / 128) * 2, 256, 0, stream>>>(
      vox2h, nullptr, nullptr, nullptr, nullptr, nullptr, nullptr,
      Wv2t, bv2, nullptr, out, 0);
}